// Round 9
// baseline (449.196 us; speedup 1.0000x reference)
//
#include <hip/hip_runtime.h>
#include <hip/hip_bf16.h>

typedef __hip_bfloat16 bf16;

#define GNUM 256
#define LN_EPS 1e-5f
#define MSG_EPS 1e-7f

typedef float f4v __attribute__((ext_vector_type(4)));
typedef short s8v __attribute__((ext_vector_type(8)));
typedef __bf16 b8v __attribute__((ext_vector_type(8)));

template <typename V>
__device__ auto mfma_bf16_(V a, V b, f4v c, int)
    -> decltype(__builtin_amdgcn_mfma_f32_16x16x32_bf16(a, b, c, 0, 0, 0)) {
  return __builtin_amdgcn_mfma_f32_16x16x32_bf16(a, b, c, 0, 0, 0);
}
template <typename V>
__device__ f4v mfma_bf16_(V a, V b, f4v c, long) {
  return __builtin_amdgcn_mfma_f32_16x16x32_bf16(__builtin_bit_cast(s8v, a),
                                                 __builtin_bit_cast(s8v, b), c, 0, 0, 0);
}
__device__ __forceinline__ f4v mfma16(uint4 a, uint4 b, f4v c){
  return mfma_bf16_(__builtin_bit_cast(b8v, a), __builtin_bit_cast(b8v, b), c, 0);
}

__device__ __forceinline__ float bu2f(unsigned short u){
  unsigned v = ((unsigned)u) << 16; return __builtin_bit_cast(float, v);
}
__device__ __forceinline__ unsigned short f2bu(float f){
  unsigned u = __builtin_bit_cast(unsigned, f);
  return (unsigned short)((u + 0x7FFFu + ((u >> 16) & 1u)) >> 16);
}

__device__ __forceinline__ float wave_sum64(float v){
  #pragma unroll
  for (int off = 32; off > 0; off >>= 1) v += __shfl_xor(v, off, 64);
  return v;
}

struct Params15 {
  const void* src[15];
  int n[15];
  int off[15];
};

// Each block re-derives the fp32-vs-bf16 flag locally, converts params to
// fp32, zeroes counts. Block 0 publishes flag for the epilogue kernels.
__global__ __launch_bounds__(256) void k_convert(Params15 P, int* __restrict__ flag,
                                                 float* __restrict__ dst,
                                                 int* __restrict__ counts, int nc){
  __shared__ int isf_sh;
  int tid = threadIdx.x;
  if (tid < 64){
    const unsigned short* u = (const unsigned short*)P.src[0];
    int bad = 0;
    for (int k = tid; k < 256; k += 64){
      unsigned short v = u[2*k];
      if (((v >> 7) & 0xFFu) >= 137u) bad = 1;
    }
    unsigned long long m = __ballot(bad);
    if (tid == 0) isf_sh = (m != 0ull) ? 1 : 0;
  }
  __syncthreads();
  bool isf = (isf_sh != 0);
  if (blockIdx.x == 0 && tid == 0) *flag = isf ? 1 : 0;
  for (int a = 0; a < 15; ++a){
    int n = P.n[a];
    float* d = dst + P.off[a];
    if (isf){
      const float* s = (const float*)P.src[a];
      for (int i = blockIdx.x*256 + tid; i < n; i += gridDim.x*256) d[i] = s[i];
    } else {
      const bf16* s = (const bf16*)P.src[a];
      for (int i = blockIdx.x*256 + tid; i < n; i += gridDim.x*256) d[i] = __bfloat162float(s[i]);
    }
  }
  for (int i = blockIdx.x*256 + tid; i < nc; i += gridDim.x*256) counts[i] = 0;
}

// ---------------- CSR build ----------------
__global__ void k_count(const int* __restrict__ dst, int* __restrict__ counts, int E){
  int e = blockIdx.x*256 + threadIdx.x;
  if (e < E) atomicAdd(counts + dst[e], 1);
}

__global__ __launch_bounds__(256) void k_scan1(const int* __restrict__ counts,
                                               int* __restrict__ offs,
                                               int* __restrict__ btot, int n){
  __shared__ int wsum[4];
  int tid = threadIdx.x, w = tid >> 6, lane = tid & 63;
  int i = blockIdx.x*256 + tid;
  int v = (i < n) ? counts[i] : 0;
  int incl = v;
  #pragma unroll
  for (int off = 1; off < 64; off <<= 1){
    int t = __shfl_up(incl, off, 64);
    if (lane >= off) incl += t;
  }
  if (lane == 63) wsum[w] = incl;
  __syncthreads();
  int woff = 0;
  for (int k = 0; k < w; ++k) woff += wsum[k];
  int tot = incl + woff;
  if (i < n) offs[i+1] = tot;
  if (tid == 255) btot[blockIdx.x] = tot;
}

__global__ __launch_bounds__(256) void k_scan2(const int* __restrict__ btot,
                                               int* __restrict__ bexc, int nb){
  __shared__ int wsum[4];
  __shared__ int carry_sh;
  int tid = threadIdx.x, w = tid >> 6, lane = tid & 63;
  if (tid == 0) carry_sh = 0;
  __syncthreads();
  for (int base = 0; base < nb; base += 256){
    int i = base + tid;
    int v = (i < nb) ? btot[i] : 0;
    int incl = v;
    #pragma unroll
    for (int off = 1; off < 64; off <<= 1){
      int t = __shfl_up(incl, off, 64);
      if (lane >= off) incl += t;
    }
    if (lane == 63) wsum[w] = incl;
    __syncthreads();
    int carry = carry_sh;
    int woff = 0;
    for (int k = 0; k < w; ++k) woff += wsum[k];
    if (i < nb) bexc[i] = carry + woff + incl - v;
    __syncthreads();
    if (tid == 0) carry_sh = carry + wsum[0] + wsum[1] + wsum[2] + wsum[3];
    __syncthreads();
  }
}

// finalize offs and seed cursor = offs
__global__ void k_scan3(int* __restrict__ offs, int* __restrict__ cursor,
                        const int* __restrict__ bexc, int n){
  int i = blockIdx.x*256 + threadIdx.x;
  if (i == 0){ offs[0] = 0; cursor[0] = 0; }
  if (i < n){
    int v = offs[i+1] + bexc[blockIdx.x];
    offs[i+1] = v;
    if (i+1 < n) cursor[i+1] = v;
  }
}

// packed payload: src (16b) | a0<<16 | a1<<19 | a2<<22
__global__ void k_scatter(const int* __restrict__ src, const int* __restrict__ dst,
                          const int* __restrict__ ea, int* __restrict__ cursor,
                          int* __restrict__ payload, int E){
  int e = blockIdx.x*256 + threadIdx.x;
  if (e >= E) return;
  int d = dst[e];
  int pos = atomicAdd(cursor + d, 1);
  payload[pos] = (src[e] & 0xFFFF) | (ea[e*3] << 16) | (ea[e*3+1] << 19) | (ea[e*3+2] << 22);
}

// blocks 0..63: permute gcn_W into MFMA B-fragment order
// blocks 64..65: goffs binary search
// blocks 66.. : node encoding  b0[i,:] = bf16(sum_f atom_emb[f,x[i,f],:] + vn_emb[:])
__global__ void k_prep(const float* __restrict__ gw, unsigned short* __restrict__ Wf,
                       const int* __restrict__ batch, int* __restrict__ goffs,
                       const int* __restrict__ x, const float* __restrict__ atom_emb,
                       const float* __restrict__ vn_emb, unsigned short* __restrict__ b0,
                       int n){
  if (blockIdx.x < 64){
    int t = blockIdx.x*256 + threadIdx.x;   // 16384 total
    int j = t & 7, lane = (t >> 3) & 63, nt = (t >> 9) & 3, kt = (t >> 11) & 1, l = t >> 12;
    int k = kt*32 + (lane >> 4)*8 + j;
    int c = nt*16 + (lane & 15);
    Wf[t] = f2bu(gw[l*4096 + k*64 + c]);
  } else if (blockIdx.x < 66){
    int g = (blockIdx.x - 64)*256 + threadIdx.x;
    if (g > GNUM) return;
    if (g == GNUM){ goffs[GNUM] = n; return; }
    int lo = 0, hi = n;
    while (lo < hi){ int mid = (lo+hi)>>1; if (batch[mid] < g) lo = mid+1; else hi = mid; }
    goffs[g] = lo;
  } else {
    int t = (blockIdx.x - 66) * 256 + threadIdx.x;
    int i = t >> 6, j = t & 63;
    if (i >= n) return;
    float acc = vn_emb[j];
    #pragma unroll
    for (int f = 0; f < 9; ++f){
      int idx = x[i*9 + f];
      acc += atom_emb[(f*64 + idx)*64 + j];
    }
    b0[t] = f2bu(acc);
  }
}

// Softmax aggregation without max-shift (msg bounded; exp safe in fp32; same
// algebra as ref). 16 nodes/block, 4 per wave (no inter-wave coupling) to
// amortize the bond-table LDS fill. 16 gathers in flight per batch
// (deg<=16 covers ~93% of nodes in one memory round-trip).
__global__ __launch_bounds__(256) void k_agg_t(
    const unsigned short* __restrict__ b0, const int* __restrict__ offs,
    const int* __restrict__ payload, const float* __restrict__ bond,
    unsigned short* __restrict__ tbuf, int n){
  __shared__ float Bs[1536];
  int tid = threadIdx.x;
  for (int idx = tid; idx < 1536; idx += 256) Bs[idx] = bond[idx];
  __syncthreads();
  int w = tid >> 6, j = tid & 63;
  int vbase = blockIdx.x * 16 + w * 4;
  #pragma unroll
  for (int q = 0; q < 4; ++q){
    int v = vbase + q;
    if (v >= n) continue;           // wave-uniform predicate
    int e0 = offs[v], e1 = offs[v+1];
    float own = bu2f(b0[(size_t)v*64 + j]);
    float tv;
    if (e1 > e0){
      float den = 0.f, num = 0.f;
      for (int e = e0; e < e1; e += 16){
        float m[16];
        #pragma unroll
        for (int u = 0; u < 16; ++u){
          int ei = e + u;
          bool valid = ei < e1;
          int idx = valid ? ei : e0;
          int p = payload[idx];
          int s = p & 0xFFFF;
          float eev = Bs[((p >> 16) & 7)*64 + j]
                    + Bs[(8 + ((p >> 19) & 7))*64 + j]
                    + Bs[(16 + ((p >> 22) & 7))*64 + j];
          float hv = bu2f(b0[(size_t)s*64 + j]);
          float mm = fmaxf(hv + eev, 0.f) + MSG_EPS;
          m[u] = valid ? mm : -100.f;   // exp(-100) ~ 0
        }
        #pragma unroll
        for (int u = 0; u < 16; ++u){
          float ex = __expf(m[u]);
          den += ex;
          num += ex * m[u];
        }
      }
      tv = own + num / fmaxf(den, 1e-16f);
    } else {
      tv = own;                     // deg-0: m = 0 (matches ref isfinite->0)
    }
    tbuf[(size_t)v*64 + j] = f2bu(tv);
  }
}

// MFMA GEMM + bias + residual + LN epilogue. 64 rows/block, 4 waves, no LDS.
// mode 0: hres = t@W+b (+hres); h2b = bf16(relu(LN(.))). mode 1: finalout = LN(.)
__global__ __launch_bounds__(256) void k_gemm_ln(
    const unsigned short* __restrict__ tbuf, const unsigned short* __restrict__ Wf,
    const float* __restrict__ bias, float* __restrict__ hres,
    unsigned short* __restrict__ h2b, void* __restrict__ finalout,
    const float* __restrict__ ng, const float* __restrict__ nb,
    const int* __restrict__ flag, int use_res, int mode, int n){
  int tid = threadIdx.x;
  int w = tid >> 6, lane = tid & 63;
  int quad = lane >> 4, lm = lane & 15;
  int v0 = blockIdx.x * 64;
  uint4 Bfr[2][4];
  const uint4* Wfv = (const uint4*)Wf;
  #pragma unroll
  for (int kt = 0; kt < 2; ++kt)
    #pragma unroll
    for (int nt = 0; nt < 4; ++nt)
      Bfr[kt][nt] = Wfv[(size_t)((kt*4 + nt)*64 + lane)];
  int arow = v0 + w*16 + lm;
  const uint4* tg = (const uint4*)tbuf;
  uint4 A0 = tg[(size_t)arow*8 + quad];
  uint4 A1 = tg[(size_t)arow*8 + 4 + quad];
  f4v acc[4];
  #pragma unroll
  for (int nt = 0; nt < 4; ++nt) acc[nt] = (f4v){0.f,0.f,0.f,0.f};
  #pragma unroll
  for (int nt = 0; nt < 4; ++nt) acc[nt] = mfma16(A0, Bfr[0][nt], acc[nt]);
  #pragma unroll
  for (int nt = 0; nt < 4; ++nt) acc[nt] = mfma16(A1, Bfr[1][nt], acc[nt]);
  float s1[4] = {0,0,0,0}, s2[4] = {0,0,0,0};
  #pragma unroll
  for (int nt = 0; nt < 4; ++nt){
    int col = nt*16 + lm;
    float bv = bias[col];
    #pragma unroll
    for (int reg = 0; reg < 4; ++reg){
      int row = v0 + w*16 + quad*4 + reg;
      float val = acc[nt][reg] + bv;
      if (use_res && row < n) val += hres[(size_t)row*64 + col];
      acc[nt][reg] = val;
      s1[reg] += val;
      s2[reg] += val*val;
    }
  }
  #pragma unroll
  for (int reg = 0; reg < 4; ++reg){
    #pragma unroll
    for (int m = 1; m < 16; m <<= 1){
      s1[reg] += __shfl_xor(s1[reg], m, 64);
      s2[reg] += __shfl_xor(s2[reg], m, 64);
    }
  }
  bool isf = (mode == 1) && (*flag != 0);
  #pragma unroll
  for (int reg = 0; reg < 4; ++reg){
    int row = v0 + w*16 + quad*4 + reg;
    if (row >= n) continue;
    float mu = s1[reg] * (1.f/64.f);
    float var = fmaxf(s2[reg] * (1.f/64.f) - mu*mu, 0.f);
    float rstd = rsqrtf(var + LN_EPS);
    #pragma unroll
    for (int nt = 0; nt < 4; ++nt){
      int col = nt*16 + lm;
      float val = acc[nt][reg];
      float y = (val - mu) * rstd * ng[col] + nb[col];
      size_t o = (size_t)row*64 + col;
      if (mode == 0){
        hres[o] = val;
        h2b[o] = f2bu(fmaxf(y, 0.f));
      } else {
        if (isf) ((float*)finalout)[o] = y;
        else     ((bf16*)finalout)[o]  = __float2bfloat16(y);
      }
    }
  }
}

// Fused virtualnode update + addvn: block g computes vn[g] (segsum + 2x MLP/LN)
// then writes b0[i,:] = bf16(h2b[i,:] + vn_g) for its OWN graph's rows.
__global__ __launch_bounds__(256) void k_vn(
    const unsigned short* __restrict__ h2b, const int* __restrict__ goffs,
    const float* __restrict__ vn_emb, float* __restrict__ vn,
    unsigned short* __restrict__ b0,
    const float* __restrict__ W1, const float* __restrict__ b1,
    const float* __restrict__ g1, const float* __restrict__ be1,
    const float* __restrict__ W2, const float* __restrict__ b2,
    const float* __restrict__ g2, const float* __restrict__ be2,
    int first){
  __shared__ float Ws[4096];
  __shared__ float part[4][64];
  __shared__ float rowbuf[64];
  __shared__ float vnew[64];
  int tid = threadIdx.x, w = tid >> 6, j = tid & 63, g = blockIdx.x;
  for (int idx = tid; idx < 4096; idx += 256) Ws[idx] = W1[idx];
  int r0 = goffs[g], r1 = goffs[g+1];
  float sum = 0.f;
  for (int i = r0 + w; i < r1; i += 4) sum += bu2f(h2b[(size_t)i*64 + j]);
  part[w][j] = sum;
  __syncthreads();
  float y = 0.f;
  if (tid < 64){
    float s = part[0][j] + part[1][j] + part[2][j] + part[3][j]
            + (first ? vn_emb[j] : vn[(size_t)g*64 + j]);
    rowbuf[j] = s;
  }
  __syncthreads();
  if (tid < 64){
    float acc = b1[j];
    #pragma unroll
    for (int k = 0; k < 64; ++k) acc = fmaf(rowbuf[k], Ws[k*64 + j], acc);
    float mu = wave_sum64(acc) * (1.f/64.f);
    float d = acc - mu;
    float var = wave_sum64(d*d) * (1.f/64.f);
    y = fmaxf(d * rsqrtf(var + LN_EPS) * g1[j] + be1[j], 0.f);
  }
  __syncthreads();
  for (int idx = tid; idx < 4096; idx += 256) Ws[idx] = W2[idx];
  if (tid < 64) rowbuf[j] = y;
  __syncthreads();
  if (tid < 64){
    float acc = b2[j];
    #pragma unroll
    for (int k = 0; k < 64; ++k) acc = fmaf(rowbuf[k], Ws[k*64 + j], acc);
    float mu = wave_sum64(acc) * (1.f/64.f);
    float d = acc - mu;
    float var = wave_sum64(d*d) * (1.f/64.f);
    float v2 = fmaxf(d * rsqrtf(var + LN_EPS) * g2[j] + be2[j], 0.f);
    vn[(size_t)g*64 + j] = v2;
    vnew[j] = v2;
  }
  __syncthreads();
  float vj = vnew[j];
  for (int i = r0 + w; i < r1; i += 4)
    b0[(size_t)i*64 + j] = f2bu(bu2f(h2b[(size_t)i*64 + j]) + vj);
}

extern "C" void kernel_launch(void* const* d_in, const int* in_sizes, int n_in,
                              void* d_out, int out_size, void* d_ws, size_t ws_size,
                              hipStream_t stream){
  const int* x          = (const int*)d_in[0];
  const int* edge_index = (const int*)d_in[1];
  const int* edge_attr  = (const int*)d_in[2];
  const int* batch      = (const int*)d_in[3];

  const int N = in_sizes[3];
  const int E = in_sizes[2] / 3;
  const int L = 4;

  const int P_ATOM = 0, P_BOND = 36864, P_GW = 38400, P_GB = 54784,
            P_NG = 55040, P_NB = 55296, P_VNE = 55552, P_W1 = 55616,
            P_B1 = 67904, P_G1 = 68096, P_BE1 = 68288, P_W2 = 68480,
            P_B2 = 80768, P_G2 = 80960, P_BE2 = 81152, P_END = 81344;

  char* ws = (char*)d_ws;
  size_t off = 0;
  auto alloc = [&](size_t bytes)->char*{
    char* p = ws + off; off += (bytes + 255) & ~(size_t)255; return p;
  };
  int*    flag   = (int*)alloc(256);
  float*  par    = (float*)alloc((size_t)P_END * 4);
  unsigned short* Wf  = (unsigned short*)alloc(16384 * 2);
  unsigned short* b0  = (unsigned short*)alloc((size_t)N*64*2);
  unsigned short* tb  = (unsigned short*)alloc((size_t)(N+64)*64*2);  // +pad for OOB frag reads
  unsigned short* h2b = (unsigned short*)alloc((size_t)N*64*2);
  float*  h      = (float*)alloc((size_t)N*64*4);
  int*    counts = (int*)alloc((size_t)N*4);
  int*    offs   = (int*)alloc((size_t)(N+1)*4);
  int*    cursor = (int*)alloc((size_t)N*4);
  int*    btot   = (int*)alloc(1024);
  int*    bexc   = (int*)alloc(1024);
  int*    payload= (int*)alloc((size_t)E*4);
  int*    goffs  = (int*)alloc((size_t)(GNUM+1)*4);
  float*  vn     = (float*)alloc((size_t)GNUM*64*4);
  (void)ws_size; (void)n_in; (void)out_size;

  Params15 P;
  const int poffs[15] = {P_ATOM,P_BOND,P_GW,P_GB,P_NG,P_NB,P_VNE,P_W1,P_B1,P_G1,P_BE1,P_W2,P_B2,P_G2,P_BE2};
  for (int a = 0; a < 15; ++a){ P.src[a] = d_in[4+a]; P.n[a] = in_sizes[4+a]; P.off[a] = poffs[a]; }

  int nodeGrid = (N*64 + 255) / 256;
  int nScanB   = (N + 255) / 256;
  int eGrid    = (E + 255) / 256;
  const int* srcp = edge_index;
  const int* dstp = edge_index + E;

  k_convert<<<128, 256, 0, stream>>>(P, flag, par, counts, N);
  k_count<<<eGrid, 256, 0, stream>>>(dstp, counts, E);
  k_scan1<<<nScanB, 256, 0, stream>>>(counts, offs, btot, N);
  k_scan2<<<1, 256, 0, stream>>>(btot, bexc, nScanB);
  k_scan3<<<nScanB, 256, 0, stream>>>(offs, cursor, bexc, N);
  k_scatter<<<eGrid, 256, 0, stream>>>(srcp, dstp, edge_attr, cursor, payload, E);
  k_prep<<<66 + nodeGrid, 256, 0, stream>>>(par + P_GW, Wf, batch, goffs,
                                            x, par + P_ATOM, par + P_VNE, b0, N);

  int gemmGrid = (N + 63) / 64;
  int aggGrid  = (N + 15) / 16;
  for (int l = 0; l < L; ++l){
    if (l > 0){
      k_vn<<<GNUM, 256, 0, stream>>>(h2b, goffs, par + P_VNE, vn, b0,
                                     par + P_W1 + (l-1)*4096, par + P_B1 + (l-1)*64,
                                     par + P_G1 + (l-1)*64, par + P_BE1 + (l-1)*64,
                                     par + P_W2 + (l-1)*4096, par + P_B2 + (l-1)*64,
                                     par + P_G2 + (l-1)*64, par + P_BE2 + (l-1)*64,
                                     l == 1 ? 1 : 0);
    }
    k_agg_t<<<aggGrid, 256, 0, stream>>>(b0, offs, payload, par + P_BOND, tb, N);
    int mode = (l == L-1) ? 1 : 0;
    k_gemm_ln<<<gemmGrid, 256, 0, stream>>>(tb, Wf + (size_t)l*4096,
                                            par + P_GB + l*64, h, h2b, d_out,
                                            par + P_NG + l*64, par + P_NB + l*64,
                                            flag, l > 0 ? 1 : 0, mode, N);
  }
}

// Round 10
// 415.978 us; speedup vs baseline: 1.0799x; 1.0799x over previous
//
#include <hip/hip_runtime.h>
#include <hip/hip_bf16.h>

typedef __hip_bfloat16 bf16;

#define GNUM 256
#define LN_EPS 1e-5f
#define MSG_EPS 1e-7f

typedef float f4v __attribute__((ext_vector_type(4)));
typedef short s8v __attribute__((ext_vector_type(8)));
typedef __bf16 b8v __attribute__((ext_vector_type(8)));

template <typename V>
__device__ auto mfma_bf16_(V a, V b, f4v c, int)
    -> decltype(__builtin_amdgcn_mfma_f32_16x16x32_bf16(a, b, c, 0, 0, 0)) {
  return __builtin_amdgcn_mfma_f32_16x16x32_bf16(a, b, c, 0, 0, 0);
}
template <typename V>
__device__ f4v mfma_bf16_(V a, V b, f4v c, long) {
  return __builtin_amdgcn_mfma_f32_16x16x32_bf16(__builtin_bit_cast(s8v, a),
                                                 __builtin_bit_cast(s8v, b), c, 0, 0, 0);
}
__device__ __forceinline__ f4v mfma16(uint4 a, uint4 b, f4v c){
  return mfma_bf16_(__builtin_bit_cast(b8v, a), __builtin_bit_cast(b8v, b), c, 0);
}

__device__ __forceinline__ float bu2f(unsigned short u){
  unsigned v = ((unsigned)u) << 16; return __builtin_bit_cast(float, v);
}
__device__ __forceinline__ unsigned short f2bu(float f){
  unsigned u = __builtin_bit_cast(unsigned, f);
  return (unsigned short)((u + 0x7FFFu + ((u >> 16) & 1u)) >> 16);
}

__device__ __forceinline__ float wave_sum64(float v){
  #pragma unroll
  for (int off = 32; off > 0; off >>= 1) v += __shfl_xor(v, off, 64);
  return v;
}

struct Params15 {
  const void* src[15];
  int n[15];
  int off[15];
};

// Each block re-derives the fp32-vs-bf16 flag locally, converts params to
// fp32, zeroes counts. Block 0 publishes flag for the epilogue kernels.
__global__ __launch_bounds__(256) void k_convert(Params15 P, int* __restrict__ flag,
                                                 float* __restrict__ dst,
                                                 int* __restrict__ counts, int nc){
  __shared__ int isf_sh;
  int tid = threadIdx.x;
  if (tid < 64){
    const unsigned short* u = (const unsigned short*)P.src[0];
    int bad = 0;
    for (int k = tid; k < 256; k += 64){
      unsigned short v = u[2*k];
      if (((v >> 7) & 0xFFu) >= 137u) bad = 1;
    }
    unsigned long long m = __ballot(bad);
    if (tid == 0) isf_sh = (m != 0ull) ? 1 : 0;
  }
  __syncthreads();
  bool isf = (isf_sh != 0);
  if (blockIdx.x == 0 && tid == 0) *flag = isf ? 1 : 0;
  for (int a = 0; a < 15; ++a){
    int n = P.n[a];
    float* d = dst + P.off[a];
    if (isf){
      const float* s = (const float*)P.src[a];
      for (int i = blockIdx.x*256 + tid; i < n; i += gridDim.x*256) d[i] = s[i];
    } else {
      const bf16* s = (const bf16*)P.src[a];
      for (int i = blockIdx.x*256 + tid; i < n; i += gridDim.x*256) d[i] = __bfloat162float(s[i]);
    }
  }
  for (int i = blockIdx.x*256 + tid; i < nc; i += gridDim.x*256) counts[i] = 0;
}

// ---------------- CSR build ----------------
__global__ void k_count(const int* __restrict__ dst, int* __restrict__ counts, int E){
  int e = blockIdx.x*256 + threadIdx.x;
  if (e < E) atomicAdd(counts + dst[e], 1);
}

__global__ __launch_bounds__(256) void k_scan1(const int* __restrict__ counts,
                                               int* __restrict__ offs,
                                               int* __restrict__ btot, int n){
  __shared__ int wsum[4];
  int tid = threadIdx.x, w = tid >> 6, lane = tid & 63;
  int i = blockIdx.x*256 + tid;
  int v = (i < n) ? counts[i] : 0;
  int incl = v;
  #pragma unroll
  for (int off = 1; off < 64; off <<= 1){
    int t = __shfl_up(incl, off, 64);
    if (lane >= off) incl += t;
  }
  if (lane == 63) wsum[w] = incl;
  __syncthreads();
  int woff = 0;
  for (int k = 0; k < w; ++k) woff += wsum[k];
  int tot = incl + woff;
  if (i < n) offs[i+1] = tot;
  if (tid == 255) btot[blockIdx.x] = tot;
}

__global__ __launch_bounds__(256) void k_scan2(const int* __restrict__ btot,
                                               int* __restrict__ bexc, int nb){
  __shared__ int wsum[4];
  __shared__ int carry_sh;
  int tid = threadIdx.x, w = tid >> 6, lane = tid & 63;
  if (tid == 0) carry_sh = 0;
  __syncthreads();
  for (int base = 0; base < nb; base += 256){
    int i = base + tid;
    int v = (i < nb) ? btot[i] : 0;
    int incl = v;
    #pragma unroll
    for (int off = 1; off < 64; off <<= 1){
      int t = __shfl_up(incl, off, 64);
      if (lane >= off) incl += t;
    }
    if (lane == 63) wsum[w] = incl;
    __syncthreads();
    int carry = carry_sh;
    int woff = 0;
    for (int k = 0; k < w; ++k) woff += wsum[k];
    if (i < nb) bexc[i] = carry + woff + incl - v;
    __syncthreads();
    if (tid == 0) carry_sh = carry + wsum[0] + wsum[1] + wsum[2] + wsum[3];
    __syncthreads();
  }
}

// finalize offs and seed cursor = offs
__global__ void k_scan3(int* __restrict__ offs, int* __restrict__ cursor,
                        const int* __restrict__ bexc, int n){
  int i = blockIdx.x*256 + threadIdx.x;
  if (i == 0){ offs[0] = 0; cursor[0] = 0; }
  if (i < n){
    int v = offs[i+1] + bexc[blockIdx.x];
    offs[i+1] = v;
    if (i+1 < n) cursor[i+1] = v;
  }
}

// packed payload: src (16b) | a0<<16 | a1<<19 | a2<<22
__global__ void k_scatter(const int* __restrict__ src, const int* __restrict__ dst,
                          const int* __restrict__ ea, int* __restrict__ cursor,
                          int* __restrict__ payload, int E){
  int e = blockIdx.x*256 + threadIdx.x;
  if (e >= E) return;
  int d = dst[e];
  int pos = atomicAdd(cursor + d, 1);
  payload[pos] = (src[e] & 0xFFFF) | (ea[e*3] << 16) | (ea[e*3+1] << 19) | (ea[e*3+2] << 22);
}

// blocks 0..63: permute gcn_W into MFMA B-fragment order
// blocks 64..65: goffs binary search
// blocks 66.. : node encoding  b0[i,:] = bf16(sum_f atom_emb[f,x[i,f],:] + vn_emb[:])
__global__ void k_prep(const float* __restrict__ gw, unsigned short* __restrict__ Wf,
                       const int* __restrict__ batch, int* __restrict__ goffs,
                       const int* __restrict__ x, const float* __restrict__ atom_emb,
                       const float* __restrict__ vn_emb, unsigned short* __restrict__ b0,
                       int n){
  if (blockIdx.x < 64){
    int t = blockIdx.x*256 + threadIdx.x;   // 16384 total
    int j = t & 7, lane = (t >> 3) & 63, nt = (t >> 9) & 3, kt = (t >> 11) & 1, l = t >> 12;
    int k = kt*32 + (lane >> 4)*8 + j;
    int c = nt*16 + (lane & 15);
    Wf[t] = f2bu(gw[l*4096 + k*64 + c]);
  } else if (blockIdx.x < 66){
    int g = (blockIdx.x - 64)*256 + threadIdx.x;
    if (g > GNUM) return;
    if (g == GNUM){ goffs[GNUM] = n; return; }
    int lo = 0, hi = n;
    while (lo < hi){ int mid = (lo+hi)>>1; if (batch[mid] < g) lo = mid+1; else hi = mid; }
    goffs[g] = lo;
  } else {
    int t = (blockIdx.x - 66) * 256 + threadIdx.x;
    int i = t >> 6, j = t & 63;
    if (i >= n) return;
    float acc = vn_emb[j];
    #pragma unroll
    for (int f = 0; f < 9; ++f){
      int idx = x[i*9 + f];
      acc += atom_emb[(f*64 + idx)*64 + j];
    }
    b0[t] = f2bu(acc);
  }
}

// Softmax aggregation without max-shift (msg bounded; exp safe in fp32; same
// algebra as ref). ONE node per wave (50k waves — latency hidden by TLP),
// batch 8 in flight; 1024-thread blocks only to amortize the 6KB bond fill
// (single post-fill barrier, no per-iteration inter-wave coupling).
__global__ __launch_bounds__(1024) void k_agg_t(
    const unsigned short* __restrict__ b0, const int* __restrict__ offs,
    const int* __restrict__ payload, const float* __restrict__ bond,
    unsigned short* __restrict__ tbuf, int n){
  __shared__ float Bs[1536];
  int tid = threadIdx.x;
  for (int idx = tid; idx < 1536; idx += 1024) Bs[idx] = bond[idx];
  __syncthreads();
  int w = tid >> 6, j = tid & 63;
  int v = blockIdx.x * 16 + w;
  if (v >= n) return;
  int e0 = offs[v], e1 = offs[v+1];
  float own = bu2f(b0[(size_t)v*64 + j]);
  float tv;
  if (e1 > e0){
    float den = 0.f, num = 0.f;
    for (int e = e0; e < e1; e += 8){
      float m[8];
      #pragma unroll
      for (int u = 0; u < 8; ++u){
        int ei = e + u;
        bool valid = ei < e1;
        int idx = valid ? ei : e0;
        int p = payload[idx];
        int s = p & 0xFFFF;
        float eev = Bs[((p >> 16) & 7)*64 + j]
                  + Bs[(8 + ((p >> 19) & 7))*64 + j]
                  + Bs[(16 + ((p >> 22) & 7))*64 + j];
        float hv = bu2f(b0[(size_t)s*64 + j]);
        float mm = fmaxf(hv + eev, 0.f) + MSG_EPS;
        m[u] = valid ? mm : -100.f;     // exp(-100) ~ 0
      }
      #pragma unroll
      for (int u = 0; u < 8; ++u){
        float ex = __expf(m[u]);
        den += ex;
        num += ex * m[u];
      }
    }
    tv = own + num / fmaxf(den, 1e-16f);
  } else {
    tv = own;                 // deg-0: m = 0 (matches ref isfinite->0)
  }
  tbuf[(size_t)v*64 + j] = f2bu(tv);
}

// MFMA GEMM + bias + residual + LN epilogue. 64 rows/block, 4 waves, no LDS.
// mode 0: hres = t@W+b (+hres); h2b = bf16(relu(LN(.))). mode 1: finalout = LN(.)
__global__ __launch_bounds__(256) void k_gemm_ln(
    const unsigned short* __restrict__ tbuf, const unsigned short* __restrict__ Wf,
    const float* __restrict__ bias, float* __restrict__ hres,
    unsigned short* __restrict__ h2b, void* __restrict__ finalout,
    const float* __restrict__ ng, const float* __restrict__ nb,
    const int* __restrict__ flag, int use_res, int mode, int n){
  int tid = threadIdx.x;
  int w = tid >> 6, lane = tid & 63;
  int quad = lane >> 4, lm = lane & 15;
  int v0 = blockIdx.x * 64;
  uint4 Bfr[2][4];
  const uint4* Wfv = (const uint4*)Wf;
  #pragma unroll
  for (int kt = 0; kt < 2; ++kt)
    #pragma unroll
    for (int nt = 0; nt < 4; ++nt)
      Bfr[kt][nt] = Wfv[(size_t)((kt*4 + nt)*64 + lane)];
  int arow = v0 + w*16 + lm;
  const uint4* tg = (const uint4*)tbuf;
  uint4 A0 = tg[(size_t)arow*8 + quad];
  uint4 A1 = tg[(size_t)arow*8 + 4 + quad];
  f4v acc[4];
  #pragma unroll
  for (int nt = 0; nt < 4; ++nt) acc[nt] = (f4v){0.f,0.f,0.f,0.f};
  #pragma unroll
  for (int nt = 0; nt < 4; ++nt) acc[nt] = mfma16(A0, Bfr[0][nt], acc[nt]);
  #pragma unroll
  for (int nt = 0; nt < 4; ++nt) acc[nt] = mfma16(A1, Bfr[1][nt], acc[nt]);
  float s1[4] = {0,0,0,0}, s2[4] = {0,0,0,0};
  #pragma unroll
  for (int nt = 0; nt < 4; ++nt){
    int col = nt*16 + lm;
    float bv = bias[col];
    #pragma unroll
    for (int reg = 0; reg < 4; ++reg){
      int row = v0 + w*16 + quad*4 + reg;
      float val = acc[nt][reg] + bv;
      if (use_res && row < n) val += hres[(size_t)row*64 + col];
      acc[nt][reg] = val;
      s1[reg] += val;
      s2[reg] += val*val;
    }
  }
  #pragma unroll
  for (int reg = 0; reg < 4; ++reg){
    #pragma unroll
    for (int m = 1; m < 16; m <<= 1){
      s1[reg] += __shfl_xor(s1[reg], m, 64);
      s2[reg] += __shfl_xor(s2[reg], m, 64);
    }
  }
  bool isf = (mode == 1) && (*flag != 0);
  #pragma unroll
  for (int reg = 0; reg < 4; ++reg){
    int row = v0 + w*16 + quad*4 + reg;
    if (row >= n) continue;
    float mu = s1[reg] * (1.f/64.f);
    float var = fmaxf(s2[reg] * (1.f/64.f) - mu*mu, 0.f);
    float rstd = rsqrtf(var + LN_EPS);
    #pragma unroll
    for (int nt = 0; nt < 4; ++nt){
      int col = nt*16 + lm;
      float val = acc[nt][reg];
      float y = (val - mu) * rstd * ng[col] + nb[col];
      size_t o = (size_t)row*64 + col;
      if (mode == 0){
        hres[o] = val;
        h2b[o] = f2bu(fmaxf(y, 0.f));
      } else {
        if (isf) ((float*)finalout)[o] = y;
        else     ((bf16*)finalout)[o]  = __float2bfloat16(y);
      }
    }
  }
}

// Fused virtualnode update + addvn: block g computes vn[g] (segsum + 2x MLP/LN)
// then writes b0[i,:] = bf16(h2b[i,:] + vn_g) for its OWN graph's rows.
__global__ __launch_bounds__(256) void k_vn(
    const unsigned short* __restrict__ h2b, const int* __restrict__ goffs,
    const float* __restrict__ vn_emb, float* __restrict__ vn,
    unsigned short* __restrict__ b0,
    const float* __restrict__ W1, const float* __restrict__ b1,
    const float* __restrict__ g1, const float* __restrict__ be1,
    const float* __restrict__ W2, const float* __restrict__ b2,
    const float* __restrict__ g2, const float* __restrict__ be2,
    int first){
  __shared__ float Ws[4096];
  __shared__ float part[4][64];
  __shared__ float rowbuf[64];
  __shared__ float vnew[64];
  int tid = threadIdx.x, w = tid >> 6, j = tid & 63, g = blockIdx.x;
  for (int idx = tid; idx < 4096; idx += 256) Ws[idx] = W1[idx];
  int r0 = goffs[g], r1 = goffs[g+1];
  float sum = 0.f;
  for (int i = r0 + w; i < r1; i += 4) sum += bu2f(h2b[(size_t)i*64 + j]);
  part[w][j] = sum;
  __syncthreads();
  float y = 0.f;
  if (tid < 64){
    float s = part[0][j] + part[1][j] + part[2][j] + part[3][j]
            + (first ? vn_emb[j] : vn[(size_t)g*64 + j]);
    rowbuf[j] = s;
  }
  __syncthreads();
  if (tid < 64){
    float acc = b1[j];
    #pragma unroll
    for (int k = 0; k < 64; ++k) acc = fmaf(rowbuf[k], Ws[k*64 + j], acc);
    float mu = wave_sum64(acc) * (1.f/64.f);
    float d = acc - mu;
    float var = wave_sum64(d*d) * (1.f/64.f);
    y = fmaxf(d * rsqrtf(var + LN_EPS) * g1[j] + be1[j], 0.f);
  }
  __syncthreads();
  for (int idx = tid; idx < 4096; idx += 256) Ws[idx] = W2[idx];
  if (tid < 64) rowbuf[j] = y;
  __syncthreads();
  if (tid < 64){
    float acc = b2[j];
    #pragma unroll
    for (int k = 0; k < 64; ++k) acc = fmaf(rowbuf[k], Ws[k*64 + j], acc);
    float mu = wave_sum64(acc) * (1.f/64.f);
    float d = acc - mu;
    float var = wave_sum64(d*d) * (1.f/64.f);
    float v2 = fmaxf(d * rsqrtf(var + LN_EPS) * g2[j] + be2[j], 0.f);
    vn[(size_t)g*64 + j] = v2;
    vnew[j] = v2;
  }
  __syncthreads();
  float vj = vnew[j];
  for (int i = r0 + w; i < r1; i += 4)
    b0[(size_t)i*64 + j] = f2bu(bu2f(h2b[(size_t)i*64 + j]) + vj);
}

extern "C" void kernel_launch(void* const* d_in, const int* in_sizes, int n_in,
                              void* d_out, int out_size, void* d_ws, size_t ws_size,
                              hipStream_t stream){
  const int* x          = (const int*)d_in[0];
  const int* edge_index = (const int*)d_in[1];
  const int* edge_attr  = (const int*)d_in[2];
  const int* batch      = (const int*)d_in[3];

  const int N = in_sizes[3];
  const int E = in_sizes[2] / 3;
  const int L = 4;

  const int P_ATOM = 0, P_BOND = 36864, P_GW = 38400, P_GB = 54784,
            P_NG = 55040, P_NB = 55296, P_VNE = 55552, P_W1 = 55616,
            P_B1 = 67904, P_G1 = 68096, P_BE1 = 68288, P_W2 = 68480,
            P_B2 = 80768, P_G2 = 80960, P_BE2 = 81152, P_END = 81344;

  char* ws = (char*)d_ws;
  size_t off = 0;
  auto alloc = [&](size_t bytes)->char*{
    char* p = ws + off; off += (bytes + 255) & ~(size_t)255; return p;
  };
  int*    flag   = (int*)alloc(256);
  float*  par    = (float*)alloc((size_t)P_END * 4);
  unsigned short* Wf  = (unsigned short*)alloc(16384 * 2);
  unsigned short* b0  = (unsigned short*)alloc((size_t)N*64*2);
  unsigned short* tb  = (unsigned short*)alloc((size_t)(N+64)*64*2);  // +pad for OOB frag reads
  unsigned short* h2b = (unsigned short*)alloc((size_t)N*64*2);
  float*  h      = (float*)alloc((size_t)N*64*4);
  int*    counts = (int*)alloc((size_t)N*4);
  int*    offs   = (int*)alloc((size_t)(N+1)*4);
  int*    cursor = (int*)alloc((size_t)N*4);
  int*    btot   = (int*)alloc(1024);
  int*    bexc   = (int*)alloc(1024);
  int*    payload= (int*)alloc((size_t)E*4);
  int*    goffs  = (int*)alloc((size_t)(GNUM+1)*4);
  float*  vn     = (float*)alloc((size_t)GNUM*64*4);
  (void)ws_size; (void)n_in; (void)out_size;

  Params15 P;
  const int poffs[15] = {P_ATOM,P_BOND,P_GW,P_GB,P_NG,P_NB,P_VNE,P_W1,P_B1,P_G1,P_BE1,P_W2,P_B2,P_G2,P_BE2};
  for (int a = 0; a < 15; ++a){ P.src[a] = d_in[4+a]; P.n[a] = in_sizes[4+a]; P.off[a] = poffs[a]; }

  int nodeGrid = (N*64 + 255) / 256;
  int nScanB   = (N + 255) / 256;
  int eGrid    = (E + 255) / 256;
  const int* srcp = edge_index;
  const int* dstp = edge_index + E;

  k_convert<<<128, 256, 0, stream>>>(P, flag, par, counts, N);
  k_count<<<eGrid, 256, 0, stream>>>(dstp, counts, E);
  k_scan1<<<nScanB, 256, 0, stream>>>(counts, offs, btot, N);
  k_scan2<<<1, 256, 0, stream>>>(btot, bexc, nScanB);
  k_scan3<<<nScanB, 256, 0, stream>>>(offs, cursor, bexc, N);
  k_scatter<<<eGrid, 256, 0, stream>>>(srcp, dstp, edge_attr, cursor, payload, E);
  k_prep<<<66 + nodeGrid, 256, 0, stream>>>(par + P_GW, Wf, batch, goffs,
                                            x, par + P_ATOM, par + P_VNE, b0, N);

  int gemmGrid = (N + 63) / 64;
  int aggGrid  = (N + 15) / 16;
  for (int l = 0; l < L; ++l){
    if (l > 0){
      k_vn<<<GNUM, 256, 0, stream>>>(h2b, goffs, par + P_VNE, vn, b0,
                                     par + P_W1 + (l-1)*4096, par + P_B1 + (l-1)*64,
                                     par + P_G1 + (l-1)*64, par + P_BE1 + (l-1)*64,
                                     par + P_W2 + (l-1)*4096, par + P_B2 + (l-1)*64,
                                     par + P_G2 + (l-1)*64, par + P_BE2 + (l-1)*64,
                                     l == 1 ? 1 : 0);
    }
    k_agg_t<<<aggGrid, 1024, 0, stream>>>(b0, offs, payload, par + P_BOND, tb, N);
    int mode = (l == L-1) ? 1 : 0;
    k_gemm_ln<<<gemmGrid, 256, 0, stream>>>(tb, Wf + (size_t)l*4096,
                                            par + P_GB + l*64, h, h2b, d_out,
                                            par + P_NG + l*64, par + P_NB + l*64,
                                            flag, l > 0 ? 1 : 0, mode, N);
  }
}